// Round 5
// baseline (383.535 us; speedup 1.0000x reference)
//
#include <hip/hip_runtime.h>

#define B_    2
#define S_    1024
#define H_    4096
#define NH_   32
#define DH_   128
#define NKV_  2
#define GROUP_ 16
#define ROT_  64
#define NQKV_ 4608   // NH*DH + 2*NKV*DH
#define SCALE_ 0.08838834764831845f  // 128^-0.5
#define KVB   64

typedef __attribute__((ext_vector_type(8))) short bf16x8;
typedef __attribute__((ext_vector_type(4))) float f32x4;

typedef __attribute__((address_space(1))) const void* gptr_t;
typedef __attribute__((address_space(3))) void* lptr_t;

__device__ __forceinline__ unsigned short f2bf(float f) {
    unsigned int u = __builtin_bit_cast(unsigned int, f);
    u += 0x7FFFu + ((u >> 16) & 1u);   // RNE
    return (unsigned short)(u >> 16);
}
__device__ __forceinline__ unsigned int pack2bf(float a, float b) {
    return (unsigned int)f2bf(a) | ((unsigned int)f2bf(b) << 16);
}

// ---------------- convert fp32 -> bf16 (vectorized) ----------------
__global__ void k_f32_to_bf16(const float* __restrict__ in,
                              unsigned short* __restrict__ out, int n4) {
    int i = blockIdx.x * blockDim.x + threadIdx.x;
    if (i >= n4) return;
    const float4 v = reinterpret_cast<const float4*>(in)[i];
    ushort4 o;
    o.x = f2bf(v.x); o.y = f2bf(v.y); o.z = f2bf(v.z); o.w = f2bf(v.w);
    reinterpret_cast<ushort4*>(out)[i] = o;
}

// ------------- transpose fp32 [K][N] -> bf16 [N][K] ----------------
__global__ void k_transpose_bf16(const float* __restrict__ in,
                                 unsigned short* __restrict__ out,
                                 int K, int N) {
    __shared__ float tile[32][33];
    const int n0 = blockIdx.x * 32, k0 = blockIdx.y * 32;
    const int tx = threadIdx.x, ty = threadIdx.y;
    for (int j = ty; j < 32; j += 8)
        tile[j][tx] = in[(size_t)(k0 + j) * N + n0 + tx];
    __syncthreads();
    for (int j = ty; j < 32; j += 8)
        out[(size_t)(n0 + j) * K + k0 + tx] = f2bf(tile[tx][j]);
}

// ------------- bf16 GEMM v3: 256x256, BK=64, 8 waves, 8-phase schedule -----
// m201 template: counted vmcnt (loads in flight across barriers), phase-split
// MFMA with setprio, XOR-swizzled LDS both-sides, bijective XCD swizzle.
// A [2048][K] bf16, Bt [N][K] bf16. grid = (N/256)*8 blocks, 512 threads.
__global__ __launch_bounds__(512) void k_gemm8(
    const unsigned short* __restrict__ A,
    const unsigned short* __restrict__ Bt,
    const float* __restrict__ bias,
    float* __restrict__ Cf,
    int N, int K, int gx)
{
    __shared__ __align__(16) char lds[2][65536];   // [buf][A 32KB | B 32KB]

    const int tid  = threadIdx.x;
    const int wave = tid >> 6, lane = tid & 63;
    const int lrow = lane & 15, lhi = lane >> 4;
    const int wm = wave >> 2, wn = wave & 3;       // 2x4 wave grid

    // bijective XCD swizzle: column-major chunks per XCD (gridDim.x % 8 == 0)
    const int id = blockIdx.x;
    const int cm = (id & 7) * gx + (id >> 3);      // column-major tile index
    const int bcol = cm >> 3, brow = cm & 7;       // 8 row-tiles (M=2048)
    const size_t a_row0 = (size_t)brow * 256;
    const size_t b_col0 = (size_t)bcol * 256;

    const size_t strideK = (size_t)K * 2;          // bytes per row
    // staging: thread covers row (chunk j)*64 + wave*8 + (lane>>3), 16B at (lane&7)*16
    const char* Asrc = (const char*)A + (a_row0 + wave * 8 + (lane >> 3)) * strideK;
    const char* Bsrc = (const char*)Bt + (b_col0 + wave * 8 + (lane >> 3)) * strideK;
    const int swz_src = ((lane & 7) * 16) ^ (((lane >> 3) & 7) << 4);
    const int dst_off = wave * 1024 + lane * 16;

    f32x4 acc[8][4] = {};
    const int nt = K >> 6;

    // ---- prologue: stage K-tile 0 -> buf 0 ----
    #pragma unroll
    for (int j = 0; j < 4; j++) {
        __builtin_amdgcn_global_load_lds(
            (gptr_t)(Asrc + (size_t)j * 64 * strideK + swz_src),
            (lptr_t)(lds[0] + j * 8192 + dst_off), 16, 0, 0);
        __builtin_amdgcn_global_load_lds(
            (gptr_t)(Bsrc + (size_t)j * 64 * strideK + swz_src),
            (lptr_t)(lds[0] + 32768 + j * 8192 + dst_off), 16, 0, 0);
    }

    int cur = 0;
    const int swz = (lrow & 7) << 4;
    for (int t = 0; t < nt; t++) {
        // issue next-tile staging; counted wait keeps it in flight
        if (t + 1 < nt) {
            const size_t kb = (size_t)(t + 1) * 128;
            #pragma unroll
            for (int j = 0; j < 4; j++) {
                __builtin_amdgcn_global_load_lds(
                    (gptr_t)(Asrc + (size_t)j * 64 * strideK + kb + swz_src),
                    (lptr_t)(lds[cur ^ 1] + j * 8192 + dst_off), 16, 0, 0);
                __builtin_amdgcn_global_load_lds(
                    (gptr_t)(Bsrc + (size_t)j * 64 * strideK + kb + swz_src),
                    (lptr_t)(lds[cur ^ 1] + 32768 + j * 8192 + dst_off), 16, 0, 0);
            }
            asm volatile("s_waitcnt vmcnt(8)" ::: "memory");   // tile t landed
        } else {
            asm volatile("s_waitcnt vmcnt(0)" ::: "memory");
        }
        __builtin_amdgcn_s_barrier();

        const char* La = lds[cur];
        const char* Lb = lds[cur] + 32768;
        // B fragments for the whole K-tile (kept in regs across phases)
        bf16x8 bfr[4][2];
        #pragma unroll
        for (int n = 0; n < 4; n++) {
            const int r = wn * 64 + n * 16 + lrow;
            bfr[n][0] = *(const bf16x8*)(Lb + r * 128 + ((lhi * 16) ^ swz));
            bfr[n][1] = *(const bf16x8*)(Lb + r * 128 + ((64 + lhi * 16) ^ swz));
        }
        // 4 phases: each {4 ds_read A-frags, setprio, 16 MFMA, barrier}
        #pragma unroll
        for (int p = 0; p < 4; p++) {
            bf16x8 af[2][2];
            #pragma unroll
            for (int i = 0; i < 2; i++) {
                const int r = wm * 128 + (p * 2 + i) * 16 + lrow;
                af[i][0] = *(const bf16x8*)(La + r * 128 + ((lhi * 16) ^ swz));
                af[i][1] = *(const bf16x8*)(La + r * 128 + ((64 + lhi * 16) ^ swz));
            }
            __builtin_amdgcn_s_setprio(1);
            #pragma unroll
            for (int i = 0; i < 2; i++)
                #pragma unroll
                for (int n = 0; n < 4; n++) {
                    acc[p * 2 + i][n] = __builtin_amdgcn_mfma_f32_16x16x32_bf16(
                        af[i][0], bfr[n][0], acc[p * 2 + i][n], 0, 0, 0);
                    acc[p * 2 + i][n] = __builtin_amdgcn_mfma_f32_16x16x32_bf16(
                        af[i][1], bfr[n][1], acc[p * 2 + i][n], 0, 0, 0);
                }
            __builtin_amdgcn_s_setprio(0);
            __builtin_amdgcn_s_barrier();
        }
        cur ^= 1;
    }

    // ---- epilogue: bias + fp32 store ----
    #pragma unroll
    for (int m = 0; m < 8; m++)
        #pragma unroll
        for (int n = 0; n < 4; n++) {
            const size_t grow0 = a_row0 + wm * 128 + m * 16 + lhi * 4;
            const size_t gcol  = b_col0 + wn * 64 + n * 16 + lrow;
            const float bi = bias ? bias[gcol] : 0.f;
            #pragma unroll
            for (int r = 0; r < 4; r++)
                Cf[(grow0 + r) * N + gcol] = acc[m][n][r] + bi;
        }
}

// ------------- RoPE (GLM interleaved, first 64 dims) + reorg -------------
__global__ void k_rope_reorg(const float* __restrict__ qkv,
                             const int* __restrict__ pos_ids,
                             unsigned short* __restrict__ Qh,
                             unsigned short* __restrict__ Kh,
                             unsigned short* __restrict__ Vt)
{
    const int NPR = (NH_ + 2 * NKV_) * 64;   // 2304 work units per token row
    const int idx = blockIdx.x * blockDim.x + threadIdx.x;
    if (idx >= B_ * S_ * NPR) return;
    const int t = idx / NPR;
    const int rem = idx % NPR;
    const int unit = rem >> 6;
    const int pr = rem & 63;
    const int b = t >> 10, s = t & 1023;
    const float pos = (float)pos_ids[t];
    const float* row = qkv + (size_t)t * NQKV_;

    if (unit < NH_) {               // Q head
        const int col = unit * DH_ + 2 * pr;
        float x0 = row[col], x1 = row[col + 1];
        if (pr < 32) {
            const float ang = pos * powf(10000.f, -(float)pr / 32.f);
            float sn, cs; sincosf(ang, &sn, &cs);
            const float o0 = x0 * cs - x1 * sn;
            const float o1 = x1 * cs + x0 * sn;
            x0 = o0; x1 = o1;
        }
        unsigned short* dst = Qh + ((size_t)((b * NH_ + unit) * S_) + s) * DH_ + 2 * pr;
        dst[0] = f2bf(x0); dst[1] = f2bf(x1);
    } else if (unit < NH_ + NKV_) { // K head
        const int g = unit - NH_;
        const int col = NH_ * DH_ + g * DH_ + 2 * pr;
        float x0 = row[col], x1 = row[col + 1];
        if (pr < 32) {
            const float ang = pos * powf(10000.f, -(float)pr / 32.f);
            float sn, cs; sincosf(ang, &sn, &cs);
            const float o0 = x0 * cs - x1 * sn;
            const float o1 = x1 * cs + x0 * sn;
            x0 = o0; x1 = o1;
        }
        unsigned short* dst = Kh + ((size_t)((b * NKV_ + g) * S_) + s) * DH_ + 2 * pr;
        dst[0] = f2bf(x0); dst[1] = f2bf(x1);
    } else {                        // V head -> transposed [DH][S]
        const int g = unit - NH_ - NKV_;
        const int col = NH_ * DH_ + NKV_ * DH_ + g * DH_ + 2 * pr;
        const float x0 = row[col], x1 = row[col + 1];
        unsigned short* d0 = Vt + ((size_t)((b * NKV_ + g) * DH_) + 2 * pr) * S_ + s;
        d0[0]  = f2bf(x0);
        d0[S_] = f2bf(x1);
    }
}

// ------------- flash attention v3: LDS-staged K/V, 2-phase pipeline --------
__global__ __launch_bounds__(256) void k_attn(
    const unsigned short* __restrict__ Qh,
    const unsigned short* __restrict__ Kh,
    const unsigned short* __restrict__ Vt,
    unsigned short* __restrict__ ctx)   // [B][S][NH*DH] bf16
{
    __shared__ __align__(16) char lds_kt[2][16384];  // K tile: 64 kv x 256B
    __shared__ __align__(16) char lds_vt[16384];     // V^T tile: 128 dh x 128B
    __shared__ __align__(16) char lds_p[4][2048];    // per-wave P: 16 q x 128B

    const int tid  = threadIdx.x;
    const int wave = tid >> 6, lane = tid & 63;
    const int lrow = lane & 15, lhi = lane >> 4;
    char* myp = lds_p[wave];

    const int blk  = blockIdx.x;
    const int pair = blk & 7;
    const int h    = (blk >> 3) & 31;
    const int b    = blk >> 8;
    const int g    = h >> 4;

    const char* Kbase = (const char*)(Kh + (size_t)((b * NKV_ + g) * S_) * DH_);
    const char* Vbase = (const char*)(Vt + (size_t)((b * NKV_ + g) * DH_) * S_);

    const int kcol = lrow * 16;          // K chunk: 4 rows x 256B, lane->row lhi
    const int vrow_l = lane >> 3;        // V chunk: 8 rows x 128B
    const int vcol = (lane & 7) * 16;

    for (int half = 0; half < 2; half++) {
        const int qt = half ? (15 - pair) : pair;
        const int q0 = qt * 64 + wave * 16;
        const int ntiles = qt + 1;
        const int q_glob = q0 + lrow;

        // ---- prologue: stage K[0] -> buf0; load Q frags ----
        #pragma unroll
        for (int i = 0; i < 4; i++) {
            const int ci = wave * 4 + i;
            const int r  = ci * 4 + lhi;
            __builtin_amdgcn_global_load_lds(
                (gptr_t)(Kbase + (size_t)r * 256 + (kcol ^ ((r & 7) << 4))),
                (lptr_t)(lds_kt[0] + ci * 1024), 16, 0, 0);
        }
        const unsigned short* Qp = Qh + ((size_t)((b * NH_ + h) * S_) + q0) * DH_;
        bf16x8 a_q[4];
        #pragma unroll
        for (int ks = 0; ks < 4; ks++)
            a_q[ks] = *(const bf16x8*)(Qp + (size_t)lrow * DH_ + ks * 32 + lhi * 8);
        asm volatile("s_waitcnt vmcnt(0)" ::: "memory");
        __builtin_amdgcn_s_barrier();

        float m_run = -1e30f, l_run = 0.f;
        f32x4 o_acc[8] = {};
        int cur = 0;

        for (int t = 0; t < ntiles; t++) {
            const bool has_next = (t + 1 < ntiles);
            // ---- issue stage V[t] (oldest 4 vmem ops) ----
            #pragma unroll
            for (int i = 0; i < 4; i++) {
                const int ci = wave * 4 + i;
                const int r  = ci * 8 + vrow_l;
                __builtin_amdgcn_global_load_lds(
                    (gptr_t)(Vbase + (size_t)r * (S_ * 2) + t * (KVB * 2)
                             + (vcol ^ ((r & 7) << 4))),
                    (lptr_t)(lds_vt + ci * 1024), 16, 0, 0);
            }
            // ---- issue stage K[t+1] -> other buffer (stays in flight) ----
            if (has_next) {
                const char* ksrc = Kbase + (size_t)(t + 1) * 16384;
                #pragma unroll
                for (int i = 0; i < 4; i++) {
                    const int ci = wave * 4 + i;
                    const int r  = ci * 4 + lhi;
                    __builtin_amdgcn_global_load_lds(
                        (gptr_t)(ksrc + (size_t)r * 256 + (kcol ^ ((r & 7) << 4))),
                        (lptr_t)(lds_kt[cur ^ 1] + ci * 1024), 16, 0, 0);
                }
            }
            // ---- S^T = K * Q^T from lds_kt[cur] (swizzled reads) ----
            f32x4 s_acc[4] = {};
            #pragma unroll
            for (int sub = 0; sub < 4; sub++) {
                const int r = sub * 16 + lrow;
                #pragma unroll
                for (int ks = 0; ks < 4; ks++) {
                    const bf16x8 a_k = *(const bf16x8*)(
                        lds_kt[cur] + r * 256 + ((ks * 64 + lhi * 16) ^ ((r & 7) << 4)));
                    s_acc[sub] = __builtin_amdgcn_mfma_f32_16x16x32_bf16(
                        a_k, a_q[ks], s_acc[sub], 0, 0, 0);
                }
            }
            // ---- lane-local online softmax (col q = lrow) ----
            float pv[16];
            float mx = -1e30f;
            if (!has_next) {          // only last tile crosses the diagonal
                #pragma unroll
                for (int sub = 0; sub < 4; sub++)
                    #pragma unroll
                    for (int r = 0; r < 4; r++) {
                        const int kvg = t * KVB + sub * 16 + lhi * 4 + r;
                        float sv = s_acc[sub][r] * SCALE_;
                        if (kvg > q_glob) sv = -1e30f;
                        pv[sub * 4 + r] = sv;
                        mx = fmaxf(mx, sv);
                    }
            } else {
                #pragma unroll
                for (int sub = 0; sub < 4; sub++)
                    #pragma unroll
                    for (int r = 0; r < 4; r++) {
                        const float sv = s_acc[sub][r] * SCALE_;
                        pv[sub * 4 + r] = sv;
                        mx = fmaxf(mx, sv);
                    }
            }
            mx = fmaxf(mx, __shfl_xor(mx, 16));
            mx = fmaxf(mx, __shfl_xor(mx, 32));
            const float mnew = fmaxf(m_run, mx);
            const float scale = __expf(m_run - mnew);
            m_run = mnew;
            float sm = 0.f;
            #pragma unroll
            for (int i = 0; i < 16; i++) {
                const float e = __expf(pv[i] - mnew);
                pv[i] = e;
                sm += e;
            }
            sm += __shfl_xor(sm, 16);
            sm += __shfl_xor(sm, 32);
            l_run = l_run * scale + sm;
            #pragma unroll
            for (int d = 0; d < 8; d++) {
                o_acc[d][0] *= scale; o_acc[d][1] *= scale;
                o_acc[d][2] *= scale; o_acc[d][3] *= scale;
            }
            // ---- P -> per-wave LDS (swizzled), read back B-fragments ----
            #pragma unroll
            for (int sub = 0; sub < 4; sub++) {
                const int off = (lrow * 128 + sub * 32 + lhi * 8) ^ ((lrow & 7) << 4);
                *reinterpret_cast<uint2*>(myp + off) = make_uint2(
                    pack2bf(pv[sub * 4 + 0], pv[sub * 4 + 1]),
                    pack2bf(pv[sub * 4 + 2], pv[sub * 4 + 3]));
            }
            bf16x8 a_p[2];
            #pragma unroll
            for (int frag = 0; frag < 2; frag++) {
                const int off = (lrow * 128 + frag * 64 + lhi * 16) ^ ((lrow & 7) << 4);
                a_p[frag] = *reinterpret_cast<const bf16x8*>(myp + off);
            }
            // ---- wait V landed (K[t+1] stays in flight), sync block ----
            if (has_next) asm volatile("s_waitcnt vmcnt(4)" ::: "memory");
            else          asm volatile("s_waitcnt vmcnt(0)" ::: "memory");
            __builtin_amdgcn_s_barrier();
            // ---- O^T += V^T * P^T from lds_vt (swizzled reads) ----
            #pragma unroll
            for (int d = 0; d < 8; d++) {
                const int r = d * 16 + lrow;
                #pragma unroll
                for (int frag = 0; frag < 2; frag++) {
                    const bf16x8 a_v = *(const bf16x8*)(
                        lds_vt + r * 128 + ((frag * 64 + lhi * 16) ^ ((r & 7) << 4)));
                    o_acc[d] = __builtin_amdgcn_mfma_f32_16x16x32_bf16(
                        a_v, a_p[frag], o_acc[d], 0, 0, 0);
                }
            }
            // ---- end of tile: K[t+1] landed, everyone done with lds_vt/kt ----
            asm volatile("s_waitcnt vmcnt(0)" ::: "memory");
            __builtin_amdgcn_s_barrier();
            cur ^= 1;
        }
        // ---- finalize: scale by 1/l (lane holds col q = lrow), store ----
        const float inv = 1.f / l_run;
        const size_t row = (size_t)b * S_ + q0 + lrow;
        #pragma unroll
        for (int d = 0; d < 8; d++) {
            unsigned short* dst = ctx + row * (NH_ * DH_) + h * DH_ + d * 16 + lhi * 4;
            *reinterpret_cast<uint2*>(dst) = make_uint2(
                pack2bf(o_acc[d][0] * inv, o_acc[d][1] * inv),
                pack2bf(o_acc[d][2] * inv, o_acc[d][3] * inv));
        }
    }
}

// --------------------------------------------------------------------------
extern "C" void kernel_launch(void* const* d_in, const int* in_sizes, int n_in,
                              void* d_out, int out_size, void* d_ws, size_t ws_size,
                              hipStream_t stream)
{
    const float* hidden  = (const float*)d_in[0];
    const int*   pos_ids = (const int*)d_in[1];
    const float* W_qkv   = (const float*)d_in[2];
    const float* b_qkv   = (const float*)d_in[3];
    const float* W_dense = (const float*)d_in[4];
    float* out = (float*)d_out;

    char* ws = (char*)d_ws;
    unsigned short* Xbf = (unsigned short*)(ws);                  // 16 MB
    unsigned short* Wqt = (unsigned short*)(ws + 16777216);       // 36 MB [4608][4096]
    unsigned short* Wdt = (unsigned short*)(ws + 54525952);       // 32 MB [4096][4096]
    float*          qkv = (float*)         (ws + 88080384);       // 36 MB [2048][4608]
    unsigned short* Qh  = (unsigned short*)(ws + 125829120);      // 16 MB
    unsigned short* Kh  = (unsigned short*)(ws + 142606336);      //  1 MB
    unsigned short* Vt  = (unsigned short*)(ws + 143654912);      //  1 MB
    unsigned short* Ctx = (unsigned short*)(ws + 144703488);      // 16 MB

    const int M = B_ * S_;   // 2048

    // 1. hidden -> bf16
    k_f32_to_bf16<<<(M * H_ / 4 + 255) / 256, 256, 0, stream>>>(hidden, Xbf, M * H_ / 4);
    // 2. weight transposes (fp32 [K][N] -> bf16 [N][K])
    dim3 tb(32, 8);
    k_transpose_bf16<<<dim3(NQKV_ / 32, H_ / 32), tb, 0, stream>>>(W_qkv, Wqt, H_, NQKV_);
    k_transpose_bf16<<<dim3(H_ / 32, H_ / 32), tb, 0, stream>>>(W_dense, Wdt, H_, H_);
    // 3. QKV projection: qkv = X @ W_qkv + b  (256x256 tiles: 18 cols x 8 rows)
    k_gemm8<<<dim3((NQKV_ / 256) * 8), 512, 0, stream>>>(
        Xbf, Wqt, b_qkv, qkv, NQKV_, H_, NQKV_ / 256);
    // 4. RoPE + head reorg + V transpose
    k_rope_reorg<<<(M * 2304 + 255) / 256, 256, 0, stream>>>(qkv, pos_ids, Qh, Kh, Vt);
    // 5. causal GQA attention -> ctx bf16 (512 blocks, 2/CU, balanced pairs)
    k_attn<<<B_ * NH_ * 8, 256, 0, stream>>>(Qh, Kh, Vt, Ctx);
    // 6. dense projection: out = ctx @ W_dense  (16 cols x 8 rows)
    k_gemm8<<<dim3((H_ / 256) * 8), 512, 0, stream>>>(
        Ctx, Wdt, nullptr, out, H_, H_, H_ / 256);
}

// Round 6
// 305.844 us; speedup vs baseline: 1.2540x; 1.2540x over previous
//
#include <hip/hip_runtime.h>

#define B_    2
#define S_    1024
#define H_    4096
#define NH_   32
#define DH_   128
#define NKV_  2
#define GROUP_ 16
#define ROT_  64
#define NQKV_ 4608   // NH*DH + 2*NKV*DH
#define SCALE_ 0.08838834764831845f  // 128^-0.5
#define KVB   64

typedef __attribute__((ext_vector_type(8))) short bf16x8;
typedef __attribute__((ext_vector_type(4))) float f32x4;

typedef __attribute__((address_space(1))) const void* gptr_t;
typedef __attribute__((address_space(3))) void* lptr_t;

__device__ __forceinline__ unsigned short f2bf(float f) {
    unsigned int u = __builtin_bit_cast(unsigned int, f);
    u += 0x7FFFu + ((u >> 16) & 1u);   // RNE
    return (unsigned short)(u >> 16);
}
__device__ __forceinline__ unsigned int pack2bf(float a, float b) {
    return (unsigned int)f2bf(a) | ((unsigned int)f2bf(b) << 16);
}

// ---------------- convert fp32 -> bf16 (vectorized) ----------------
__global__ void k_f32_to_bf16(const float* __restrict__ in,
                              unsigned short* __restrict__ out, int n4) {
    int i = blockIdx.x * blockDim.x + threadIdx.x;
    if (i >= n4) return;
    const float4 v = reinterpret_cast<const float4*>(in)[i];
    ushort4 o;
    o.x = f2bf(v.x); o.y = f2bf(v.y); o.z = f2bf(v.z); o.w = f2bf(v.w);
    reinterpret_cast<ushort4*>(out)[i] = o;
}

// ------------- transpose fp32 [K][N] -> bf16 [N][K] ----------------
__global__ void k_transpose_bf16(const float* __restrict__ in,
                                 unsigned short* __restrict__ out,
                                 int K, int N) {
    __shared__ float tile[32][33];
    const int n0 = blockIdx.x * 32, k0 = blockIdx.y * 32;
    const int tx = threadIdx.x, ty = threadIdx.y;
    for (int j = ty; j < 32; j += 8)
        tile[j][tx] = in[(size_t)(k0 + j) * N + n0 + tx];
    __syncthreads();
    for (int j = ty; j < 32; j += 8)
        out[(size_t)(n0 + j) * K + k0 + tx] = f2bf(tile[tx][j]);
}

// ------------- bf16 GEMM v4: 128x128 tile, BK=64, 4 waves, dbuf ------------
// Small LDS (64 KB) + big grid (512/576 blocks) -> 2 blocks/CU co-resident:
// cross-block wave overlap absorbs the vmcnt+barrier drains (m97/m114
// mechanism). Counted vmcnt(8) keeps next tile in flight across the barrier.
// A [M][K] bf16, Bt [N][K] bf16, XOR-swizzled LDS both-sides.
__global__ __launch_bounds__(256, 2) void k_gemm_bt(
    const unsigned short* __restrict__ A,
    const unsigned short* __restrict__ Bt,
    const float* __restrict__ bias,
    float* __restrict__ Cf,
    int M, int N, int K)
{
    __shared__ __align__(16) char lds[2][32768];   // [buf][A 16KB | B 16KB]

    const int tid  = threadIdx.x;
    const int wave = tid >> 6, lane = tid & 63;
    const int lrow = lane & 15, lhi = lane >> 4;
    const int wm = (wave >> 1) * 64, wn = (wave & 1) * 64;
    const size_t a_row0 = (size_t)blockIdx.y * 128;
    const size_t b_col0 = (size_t)blockIdx.x * 128;

    const size_t strideK = (size_t)K * 2;          // bytes per row
    // staging: round j covers LDS bytes [j*4096 + tid*16]; row = j*32 + tid/8
    const char* Asrc = (const char*)A + (a_row0 + (tid >> 3)) * strideK;
    const char* Bsrc = (const char*)Bt + (b_col0 + (tid >> 3)) * strideK;
    const int swz_src = ((tid & 7) * 16) ^ (((tid >> 3) & 7) << 4);
    const int dst_off = tid * 16;

    f32x4 acc[4][4] = {};
    const int nt = K >> 6;   // BK=64

    // ---- prologue: stage tile 0 -> buf 0 (8 gloads/thread) ----
    #pragma unroll
    for (int j = 0; j < 4; j++) {
        __builtin_amdgcn_global_load_lds(
            (gptr_t)(Asrc + (size_t)j * 32 * strideK + swz_src),
            (lptr_t)(lds[0] + j * 4096 + dst_off), 16, 0, 0);
        __builtin_amdgcn_global_load_lds(
            (gptr_t)(Bsrc + (size_t)j * 32 * strideK + swz_src),
            (lptr_t)(lds[0] + 16384 + j * 4096 + dst_off), 16, 0, 0);
    }

    int cur = 0;
    for (int t = 0; t < nt; t++) {
        // ---- issue next-tile staging; counted wait keeps it in flight ----
        if (t + 1 < nt) {
            const size_t kb = (size_t)(t + 1) * 128;   // BK=64 -> 128 bytes
            #pragma unroll
            for (int j = 0; j < 4; j++) {
                __builtin_amdgcn_global_load_lds(
                    (gptr_t)(Asrc + (size_t)j * 32 * strideK + kb + swz_src),
                    (lptr_t)(lds[cur ^ 1] + j * 4096 + dst_off), 16, 0, 0);
                __builtin_amdgcn_global_load_lds(
                    (gptr_t)(Bsrc + (size_t)j * 32 * strideK + kb + swz_src),
                    (lptr_t)(lds[cur ^ 1] + 16384 + j * 4096 + dst_off), 16, 0, 0);
            }
            asm volatile("s_waitcnt vmcnt(8)" ::: "memory");   // tile t landed
        } else {
            asm volatile("s_waitcnt vmcnt(0)" ::: "memory");
        }
        __builtin_amdgcn_s_barrier();

        // ---- fragments from buf[cur] (swizzled reads) ----
        const char* La = lds[cur];
        const char* Lb = lds[cur] + 16384;
        bf16x8 af[4][2], bfr[4][2];
        #pragma unroll
        for (int i = 0; i < 4; i++) {
            const int fr = wm + i * 16 + lrow;
            af[i][0] = *(const bf16x8*)(La + fr * 128 + ((lhi * 16) ^ ((fr & 7) << 4)));
            af[i][1] = *(const bf16x8*)(La + fr * 128 + ((64 + lhi * 16) ^ ((fr & 7) << 4)));
        }
        #pragma unroll
        for (int j = 0; j < 4; j++) {
            const int br = wn + j * 16 + lrow;
            bfr[j][0] = *(const bf16x8*)(Lb + br * 128 + ((lhi * 16) ^ ((br & 7) << 4)));
            bfr[j][1] = *(const bf16x8*)(Lb + br * 128 + ((64 + lhi * 16) ^ ((br & 7) << 4)));
        }
        #pragma unroll
        for (int i = 0; i < 4; i++)
            #pragma unroll
            for (int j = 0; j < 4; j++) {
                acc[i][j] = __builtin_amdgcn_mfma_f32_16x16x32_bf16(
                    af[i][0], bfr[j][0], acc[i][j], 0, 0, 0);
                acc[i][j] = __builtin_amdgcn_mfma_f32_16x16x32_bf16(
                    af[i][1], bfr[j][1], acc[i][j], 0, 0, 0);
            }
        // all waves done with buf[cur] before next iter overwrites it
        __builtin_amdgcn_s_barrier();
        cur ^= 1;
    }

    // ---- epilogue: bias + fp32 store ----
    #pragma unroll
    for (int i = 0; i < 4; i++)
        #pragma unroll
        for (int j = 0; j < 4; j++) {
            const size_t grow0 = a_row0 + wm + i * 16 + lhi * 4;
            const size_t gcol  = b_col0 + wn + j * 16 + lrow;
            const float bi = bias ? bias[gcol] : 0.f;
            #pragma unroll
            for (int r = 0; r < 4; r++)
                Cf[(grow0 + r) * N + gcol] = acc[i][j][r] + bi;
        }
}

// ------------- RoPE (GLM interleaved, first 64 dims) + reorg -------------
__global__ void k_rope_reorg(const float* __restrict__ qkv,
                             const int* __restrict__ pos_ids,
                             unsigned short* __restrict__ Qh,
                             unsigned short* __restrict__ Kh,
                             unsigned short* __restrict__ Vt)
{
    const int NPR = (NH_ + 2 * NKV_) * 64;   // 2304 work units per token row
    const int idx = blockIdx.x * blockDim.x + threadIdx.x;
    if (idx >= B_ * S_ * NPR) return;
    const int t = idx / NPR;
    const int rem = idx % NPR;
    const int unit = rem >> 6;
    const int pr = rem & 63;
    const int b = t >> 10, s = t & 1023;
    const float pos = (float)pos_ids[t];
    const float* row = qkv + (size_t)t * NQKV_;

    if (unit < NH_) {               // Q head
        const int col = unit * DH_ + 2 * pr;
        float x0 = row[col], x1 = row[col + 1];
        if (pr < 32) {
            const float ang = pos * powf(10000.f, -(float)pr / 32.f);
            float sn, cs; sincosf(ang, &sn, &cs);
            const float o0 = x0 * cs - x1 * sn;
            const float o1 = x1 * cs + x0 * sn;
            x0 = o0; x1 = o1;
        }
        unsigned short* dst = Qh + ((size_t)((b * NH_ + unit) * S_) + s) * DH_ + 2 * pr;
        dst[0] = f2bf(x0); dst[1] = f2bf(x1);
    } else if (unit < NH_ + NKV_) { // K head
        const int g = unit - NH_;
        const int col = NH_ * DH_ + g * DH_ + 2 * pr;
        float x0 = row[col], x1 = row[col + 1];
        if (pr < 32) {
            const float ang = pos * powf(10000.f, -(float)pr / 32.f);
            float sn, cs; sincosf(ang, &sn, &cs);
            const float o0 = x0 * cs - x1 * sn;
            const float o1 = x1 * cs + x0 * sn;
            x0 = o0; x1 = o1;
        }
        unsigned short* dst = Kh + ((size_t)((b * NKV_ + g) * S_) + s) * DH_ + 2 * pr;
        dst[0] = f2bf(x0); dst[1] = f2bf(x1);
    } else {                        // V head -> transposed [DH][S]
        const int g = unit - NH_ - NKV_;
        const int col = NH_ * DH_ + NKV_ * DH_ + g * DH_ + 2 * pr;
        const float x0 = row[col], x1 = row[col + 1];
        unsigned short* d0 = Vt + ((size_t)((b * NKV_ + g) * DH_) + 2 * pr) * S_ + s;
        d0[0]  = f2bf(x0);
        d0[S_] = f2bf(x1);
    }
}

// ------------- flash attention v3: LDS-staged K/V, 2-phase pipeline --------
__global__ __launch_bounds__(256) void k_attn(
    const unsigned short* __restrict__ Qh,
    const unsigned short* __restrict__ Kh,
    const unsigned short* __restrict__ Vt,
    unsigned short* __restrict__ ctx)   // [B][S][NH*DH] bf16
{
    __shared__ __align__(16) char lds_kt[2][16384];  // K tile: 64 kv x 256B
    __shared__ __align__(16) char lds_vt[16384];     // V^T tile: 128 dh x 128B
    __shared__ __align__(16) char lds_p[4][2048];    // per-wave P: 16 q x 128B

    const int tid  = threadIdx.x;
    const int wave = tid >> 6, lane = tid & 63;
    const int lrow = lane & 15, lhi = lane >> 4;
    char* myp = lds_p[wave];

    const int blk  = blockIdx.x;
    const int pair = blk & 7;
    const int h    = (blk >> 3) & 31;
    const int b    = blk >> 8;
    const int g    = h >> 4;

    const char* Kbase = (const char*)(Kh + (size_t)((b * NKV_ + g) * S_) * DH_);
    const char* Vbase = (const char*)(Vt + (size_t)((b * NKV_ + g) * DH_) * S_);

    const int kcol = lrow * 16;          // K chunk: 4 rows x 256B, lane->row lhi
    const int vrow_l = lane >> 3;        // V chunk: 8 rows x 128B
    const int vcol = (lane & 7) * 16;

    for (int half = 0; half < 2; half++) {
        const int qt = half ? (15 - pair) : pair;
        const int q0 = qt * 64 + wave * 16;
        const int ntiles = qt + 1;
        const int q_glob = q0 + lrow;

        // ---- prologue: stage K[0] -> buf0; load Q frags ----
        #pragma unroll
        for (int i = 0; i < 4; i++) {
            const int ci = wave * 4 + i;
            const int r  = ci * 4 + lhi;
            __builtin_amdgcn_global_load_lds(
                (gptr_t)(Kbase + (size_t)r * 256 + (kcol ^ ((r & 7) << 4))),
                (lptr_t)(lds_kt[0] + ci * 1024), 16, 0, 0);
        }
        const unsigned short* Qp = Qh + ((size_t)((b * NH_ + h) * S_) + q0) * DH_;
        bf16x8 a_q[4];
        #pragma unroll
        for (int ks = 0; ks < 4; ks++)
            a_q[ks] = *(const bf16x8*)(Qp + (size_t)lrow * DH_ + ks * 32 + lhi * 8);
        asm volatile("s_waitcnt vmcnt(0)" ::: "memory");
        __builtin_amdgcn_s_barrier();

        float m_run = -1e30f, l_run = 0.f;
        f32x4 o_acc[8] = {};
        int cur = 0;

        for (int t = 0; t < ntiles; t++) {
            const bool has_next = (t + 1 < ntiles);
            // ---- issue stage V[t] (oldest 4 vmem ops) ----
            #pragma unroll
            for (int i = 0; i < 4; i++) {
                const int ci = wave * 4 + i;
                const int r  = ci * 8 + vrow_l;
                __builtin_amdgcn_global_load_lds(
                    (gptr_t)(Vbase + (size_t)r * (S_ * 2) + t * (KVB * 2)
                             + (vcol ^ ((r & 7) << 4))),
                    (lptr_t)(lds_vt + ci * 1024), 16, 0, 0);
            }
            // ---- issue stage K[t+1] -> other buffer (stays in flight) ----
            if (has_next) {
                const char* ksrc = Kbase + (size_t)(t + 1) * 16384;
                #pragma unroll
                for (int i = 0; i < 4; i++) {
                    const int ci = wave * 4 + i;
                    const int r  = ci * 4 + lhi;
                    __builtin_amdgcn_global_load_lds(
                        (gptr_t)(ksrc + (size_t)r * 256 + (kcol ^ ((r & 7) << 4))),
                        (lptr_t)(lds_kt[cur ^ 1] + ci * 1024), 16, 0, 0);
                }
            }
            // ---- S^T = K * Q^T from lds_kt[cur] (swizzled reads) ----
            f32x4 s_acc[4] = {};
            #pragma unroll
            for (int sub = 0; sub < 4; sub++) {
                const int r = sub * 16 + lrow;
                #pragma unroll
                for (int ks = 0; ks < 4; ks++) {
                    const bf16x8 a_k = *(const bf16x8*)(
                        lds_kt[cur] + r * 256 + ((ks * 64 + lhi * 16) ^ ((r & 7) << 4)));
                    s_acc[sub] = __builtin_amdgcn_mfma_f32_16x16x32_bf16(
                        a_k, a_q[ks], s_acc[sub], 0, 0, 0);
                }
            }
            // ---- lane-local online softmax (col q = lrow) ----
            float pv[16];
            float mx = -1e30f;
            if (!has_next) {          // only last tile crosses the diagonal
                #pragma unroll
                for (int sub = 0; sub < 4; sub++)
                    #pragma unroll
                    for (int r = 0; r < 4; r++) {
                        const int kvg = t * KVB + sub * 16 + lhi * 4 + r;
                        float sv = s_acc[sub][r] * SCALE_;
                        if (kvg > q_glob) sv = -1e30f;
                        pv[sub * 4 + r] = sv;
                        mx = fmaxf(mx, sv);
                    }
            } else {
                #pragma unroll
                for (int sub = 0; sub < 4; sub++)
                    #pragma unroll
                    for (int r = 0; r < 4; r++) {
                        const float sv = s_acc[sub][r] * SCALE_;
                        pv[sub * 4 + r] = sv;
                        mx = fmaxf(mx, sv);
                    }
            }
            mx = fmaxf(mx, __shfl_xor(mx, 16));
            mx = fmaxf(mx, __shfl_xor(mx, 32));
            const float mnew = fmaxf(m_run, mx);
            const float scale = __expf(m_run - mnew);
            m_run = mnew;
            float sm = 0.f;
            #pragma unroll
            for (int i = 0; i < 16; i++) {
                const float e = __expf(pv[i] - mnew);
                pv[i] = e;
                sm += e;
            }
            sm += __shfl_xor(sm, 16);
            sm += __shfl_xor(sm, 32);
            l_run = l_run * scale + sm;
            #pragma unroll
            for (int d = 0; d < 8; d++) {
                o_acc[d][0] *= scale; o_acc[d][1] *= scale;
                o_acc[d][2] *= scale; o_acc[d][3] *= scale;
            }
            // ---- P -> per-wave LDS (swizzled), read back B-fragments ----
            #pragma unroll
            for (int sub = 0; sub < 4; sub++) {
                const int off = (lrow * 128 + sub * 32 + lhi * 8) ^ ((lrow & 7) << 4);
                *reinterpret_cast<uint2*>(myp + off) = make_uint2(
                    pack2bf(pv[sub * 4 + 0], pv[sub * 4 + 1]),
                    pack2bf(pv[sub * 4 + 2], pv[sub * 4 + 3]));
            }
            bf16x8 a_p[2];
            #pragma unroll
            for (int frag = 0; frag < 2; frag++) {
                const int off = (lrow * 128 + frag * 64 + lhi * 16) ^ ((lrow & 7) << 4);
                a_p[frag] = *reinterpret_cast<const bf16x8*>(myp + off);
            }
            // ---- wait V landed (K[t+1] stays in flight), sync block ----
            if (has_next) asm volatile("s_waitcnt vmcnt(4)" ::: "memory");
            else          asm volatile("s_waitcnt vmcnt(0)" ::: "memory");
            __builtin_amdgcn_s_barrier();
            // ---- O^T += V^T * P^T from lds_vt (swizzled reads) ----
            #pragma unroll
            for (int d = 0; d < 8; d++) {
                const int r = d * 16 + lrow;
                #pragma unroll
                for (int frag = 0; frag < 2; frag++) {
                    const bf16x8 a_v = *(const bf16x8*)(
                        lds_vt + r * 128 + ((frag * 64 + lhi * 16) ^ ((r & 7) << 4)));
                    o_acc[d] = __builtin_amdgcn_mfma_f32_16x16x32_bf16(
                        a_v, a_p[frag], o_acc[d], 0, 0, 0);
                }
            }
            // ---- end of tile: K[t+1] landed, everyone done with lds_vt/kt ----
            asm volatile("s_waitcnt vmcnt(0)" ::: "memory");
            __builtin_amdgcn_s_barrier();
            cur ^= 1;
        }
        // ---- finalize: scale by 1/l (lane holds col q = lrow), store ----
        const float inv = 1.f / l_run;
        const size_t row = (size_t)b * S_ + q0 + lrow;
        #pragma unroll
        for (int d = 0; d < 8; d++) {
            unsigned short* dst = ctx + row * (NH_ * DH_) + h * DH_ + d * 16 + lhi * 4;
            *reinterpret_cast<uint2*>(dst) = make_uint2(
                pack2bf(o_acc[d][0] * inv, o_acc[d][1] * inv),
                pack2bf(o_acc[d][2] * inv, o_acc[d][3] * inv));
        }
    }
}

// --------------------------------------------------------------------------
extern "C" void kernel_launch(void* const* d_in, const int* in_sizes, int n_in,
                              void* d_out, int out_size, void* d_ws, size_t ws_size,
                              hipStream_t stream)
{
    const float* hidden  = (const float*)d_in[0];
    const int*   pos_ids = (const int*)d_in[1];
    const float* W_qkv   = (const float*)d_in[2];
    const float* b_qkv   = (const float*)d_in[3];
    const float* W_dense = (const float*)d_in[4];
    float* out = (float*)d_out;

    char* ws = (char*)d_ws;
    unsigned short* Xbf = (unsigned short*)(ws);                  // 16 MB
    unsigned short* Wqt = (unsigned short*)(ws + 16777216);       // 36 MB [4608][4096]
    unsigned short* Wdt = (unsigned short*)(ws + 54525952);       // 32 MB [4096][4096]
    float*          qkv = (float*)         (ws + 88080384);       // 36 MB [2048][4608]
    unsigned short* Qh  = (unsigned short*)(ws + 125829120);      // 16 MB
    unsigned short* Kh  = (unsigned short*)(ws + 142606336);      //  1 MB
    unsigned short* Vt  = (unsigned short*)(ws + 143654912);      //  1 MB
    unsigned short* Ctx = (unsigned short*)(ws + 144703488);      // 16 MB

    const int M = B_ * S_;   // 2048

    // 1. hidden -> bf16
    k_f32_to_bf16<<<(M * H_ / 4 + 255) / 256, 256, 0, stream>>>(hidden, Xbf, M * H_ / 4);
    // 2. weight transposes (fp32 [K][N] -> bf16 [N][K])
    dim3 tb(32, 8);
    k_transpose_bf16<<<dim3(NQKV_ / 32, H_ / 32), tb, 0, stream>>>(W_qkv, Wqt, H_, NQKV_);
    k_transpose_bf16<<<dim3(H_ / 32, H_ / 32), tb, 0, stream>>>(W_dense, Wdt, H_, H_);
    // 3. QKV projection: qkv = X @ W_qkv + b   (36 x 16 = 576 blocks)
    k_gemm_bt<<<dim3(NQKV_ / 128, M / 128), 256, 0, stream>>>(
        Xbf, Wqt, b_qkv, qkv, M, NQKV_, H_);
    // 4. RoPE + head reorg + V transpose
    k_rope_reorg<<<(M * 2304 + 255) / 256, 256, 0, stream>>>(qkv, pos_ids, Qh, Kh, Vt);
    // 5. causal GQA attention -> ctx bf16 (512 blocks, 2/CU, balanced pairs)
    k_attn<<<B_ * NH_ * 8, 256, 0, stream>>>(Qh, Kh, Vt, Ctx);
    // 6. dense projection: out = ctx @ W_dense   (32 x 16 = 512 blocks)
    k_gemm_bt<<<dim3(H_ / 128, M / 128), 256, 0, stream>>>(
        Ctx, Wdt, nullptr, out, M, H_, H_);
}